// Round 1
// baseline (530.498 us; speedup 1.0000x reference)
//
#include <hip/hip_runtime.h>

#define T_LEN 512
#define B_SZ  256
#define N_ST  128

// ws layout (floats): [0..255] logZ_b ; [256..511] score_b ; [512..767] lens (as int)

__global__ void lengths_kernel(const unsigned char* __restrict__ mask_raw,
                               int* __restrict__ lens) {
    int b = threadIdx.x;  // 256 threads, 1 block
    // Detect mask encoding. mask[0][b] is always true (lengths >= T/2 >= 1).
    // u8 : byte[1] = mask[0][1] = 1
    // i32: byte[1] = high byte of mask[0][0] = 0, byte[2] = 0
    // f32: 1.0f = {0,0,0x80,0x3f} -> byte[1] = 0, byte[2] = 0x80
    unsigned char b1 = mask_raw[1];
    unsigned char b2 = mask_raw[2];
    int mode = (b1 != 0) ? 0 : ((b2 != 0) ? 2 : 1);
    int len = 0;
    if (mode == 0) {
        for (int t = 0; t < T_LEN; ++t) len += (mask_raw[t * B_SZ + b] != 0);
    } else if (mode == 1) {
        const int* m = (const int*)mask_raw;
        for (int t = 0; t < T_LEN; ++t) len += (m[t * B_SZ + b] != 0);
    } else {
        const float* m = (const float*)mask_raw;
        for (int t = 0; t < T_LEN; ++t) len += (m[t * B_SZ + b] != 0.0f);
    }
    lens[b] = len;
}

__global__ __launch_bounds__(256) void forward_kernel(
        const float* __restrict__ emit,
        const float* __restrict__ trans,
        const float* __restrict__ strans,
        const float* __restrict__ etrans,
        const int* __restrict__ lens,
        float* __restrict__ logZ_out) {
    const int b   = blockIdx.x;
    const int tid = threadIdx.x;
    const int h   = tid >> 7;    // i-half: 0 -> i in [0,64), 1 -> [64,128)
    const int j   = tid & 127;   // output column (replicated across h)

    __shared__ float a_sh[N_ST];
    __shared__ float s_lds[2 * N_ST];
    __shared__ float wred[4];

    // E[h*64+k][j] = exp(trans[i][j]) held in registers; reused T*len times.
    float Ecol[64];
    #pragma unroll
    for (int k = 0; k < 64; ++k)
        Ecol[k] = __expf(trans[(h * 64 + k) * N_ST + j]);

    float alpha = strans[j] + emit[(size_t)b * N_ST + j];
    const int len = lens[b];

    for (int t = 1; t < len; ++t) {
        // block max of alpha (each value present twice; max unaffected)
        float m = alpha;
        #pragma unroll
        for (int off = 1; off < 64; off <<= 1)
            m = fmaxf(m, __shfl_xor(m, off));
        if ((tid & 63) == 0) wred[tid >> 6] = m;
        __syncthreads();
        float M = fmaxf(fmaxf(wred[0], wred[1]), fmaxf(wred[2], wred[3]));
        float a = __expf(alpha - M);
        if (h == 0) a_sh[j] = a;
        __syncthreads();

        // partial matvec: s_h[j] = sum_{i in half h} a[i] * E[i][j]
        float s0 = 0.f, s1 = 0.f, s2 = 0.f, s3 = 0.f;
        const float4* a4 = (const float4*)&a_sh[h * 64];
        #pragma unroll
        for (int k = 0; k < 16; ++k) {
            float4 av = a4[k];
            s0 = __builtin_fmaf(av.x, Ecol[4 * k + 0], s0);
            s1 = __builtin_fmaf(av.y, Ecol[4 * k + 1], s1);
            s2 = __builtin_fmaf(av.z, Ecol[4 * k + 2], s2);
            s3 = __builtin_fmaf(av.w, Ecol[4 * k + 3], s3);
        }
        s_lds[h * N_ST + j] = (s0 + s1) + (s2 + s3);
        __syncthreads();
        float stot = s_lds[j] + s_lds[N_ST + j];
        alpha = emit[(size_t)t * (B_SZ * N_ST) + b * N_ST + j] + M + __logf(stot);
    }

    // logZ_b = logsumexp_j(alpha_j + etrans_j)
    float v = alpha + etrans[j];
    float m = v;
    #pragma unroll
    for (int off = 1; off < 64; off <<= 1)
        m = fmaxf(m, __shfl_xor(m, off));
    if ((tid & 63) == 0) wred[tid >> 6] = m;
    __syncthreads();
    float M2 = fmaxf(fmaxf(wred[0], wred[1]), fmaxf(wred[2], wred[3]));
    float e = __expf(v - M2);
    float ssum = e;
    #pragma unroll
    for (int off = 1; off < 64; off <<= 1)
        ssum += __shfl_xor(ssum, off);
    __syncthreads();  // WAR: protect s_lds reuse vs last-iteration reads
    if ((tid & 63) == 0) s_lds[tid >> 6] = ssum;
    __syncthreads();
    if (tid == 0) logZ_out[b] = M2 + __logf(s_lds[0] + s_lds[1]);  // waves 0,1 cover j=0..127
}

__global__ __launch_bounds__(128) void score_kernel(
        const float* __restrict__ emit,
        const int* __restrict__ target,
        const float* __restrict__ trans,
        const float* __restrict__ strans,
        const float* __restrict__ etrans,
        const int* __restrict__ lens,
        float* __restrict__ score_out) {
    const int b   = blockIdx.x;
    const int tid = threadIdx.x;  // 128
    const int len = lens[b];
    float local = 0.f;
    for (int t = tid; t < len; t += 128) {
        int tgt = target[t * B_SZ + b];
        float v = emit[(size_t)t * (B_SZ * N_ST) + b * N_ST + tgt];
        if (t > 0) v += trans[target[(t - 1) * B_SZ + b] * N_ST + tgt];
        local += v;
    }
    if (tid == 0) {
        local += strans[target[b]];
        local += etrans[target[(len - 1) * B_SZ + b]];
    }
    #pragma unroll
    for (int off = 1; off < 64; off <<= 1) local += __shfl_xor(local, off);
    __shared__ float partial[2];
    if ((tid & 63) == 0) partial[tid >> 6] = local;
    __syncthreads();
    if (tid == 0) score_out[b] = partial[0] + partial[1];
}

__global__ __launch_bounds__(256) void finalize_kernel(
        const float* __restrict__ logZ,
        const float* __restrict__ score,
        float* __restrict__ out) {
    int tid = threadIdx.x;  // 256
    float v = logZ[tid] - score[tid];
    #pragma unroll
    for (int off = 1; off < 64; off <<= 1) v += __shfl_xor(v, off);
    __shared__ float p[4];
    if ((tid & 63) == 0) p[tid >> 6] = v;
    __syncthreads();
    if (tid == 0) out[0] = (p[0] + p[1] + p[2] + p[3]) / 256.0f;
}

extern "C" void kernel_launch(void* const* d_in, const int* in_sizes, int n_in,
                              void* d_out, int out_size, void* d_ws, size_t ws_size,
                              hipStream_t stream) {
    const float*         emit   = (const float*)d_in[0];
    const int*           target = (const int*)d_in[1];
    const unsigned char* mask   = (const unsigned char*)d_in[2];
    const float*         trans  = (const float*)d_in[3];
    const float*         strans = (const float*)d_in[4];
    const float*         etrans = (const float*)d_in[5];

    float* ws     = (float*)d_ws;
    float* logZb  = ws;            // 256
    float* scoreb = ws + 256;      // 256
    int*   lens   = (int*)(ws + 512);

    lengths_kernel<<<1, 256, 0, stream>>>(mask, lens);
    forward_kernel<<<B_SZ, 256, 0, stream>>>(emit, trans, strans, etrans, lens, logZb);
    score_kernel<<<B_SZ, 128, 0, stream>>>(emit, target, trans, strans, etrans, lens, scoreb);
    finalize_kernel<<<1, 256, 0, stream>>>(logZb, scoreb, (float*)d_out);
}

// Round 2
// 327.030 us; speedup vs baseline: 1.6222x; 1.6222x over previous
//
#include <hip/hip_runtime.h>

#define T_LEN 512
#define B_SZ  256
#define N_ST  128

// ws layout (floats): [0..255] logZ_b ; [256..511] score_b ; [512..767] lens (int)

__global__ __launch_bounds__(64) void lengths_kernel(const unsigned char* __restrict__ mask_raw,
                                                     int* __restrict__ lens) {
    int b = blockIdx.x;   // 256 blocks
    int l = threadIdx.x;  // 64 threads
    // Detect mask encoding (mask[0][*] is always true since lengths >= T/2):
    // u8 : byte[1]=mask[0][1]=1 ; i32: bytes 1,2 = 0 ; f32: 1.0f -> byte[2]=0x80
    unsigned char b1 = mask_raw[1], b2 = mask_raw[2];
    int mode = (b1 != 0) ? 0 : ((b2 != 0) ? 2 : 1);
    int cnt = 0;
    if (mode == 0) {
        #pragma unroll
        for (int k = 0; k < 8; ++k) cnt += (mask_raw[(l * 8 + k) * B_SZ + b] != 0);
    } else if (mode == 1) {
        const int* m = (const int*)mask_raw;
        #pragma unroll
        for (int k = 0; k < 8; ++k) cnt += (m[(l * 8 + k) * B_SZ + b] != 0);
    } else {
        const float* m = (const float*)mask_raw;
        #pragma unroll
        for (int k = 0; k < 8; ++k) cnt += (m[(l * 8 + k) * B_SZ + b] != 0.0f);
    }
    #pragma unroll
    for (int off = 1; off < 64; off <<= 1) cnt += __shfl_xor(cnt, off);
    if (l == 0) lens[b] = cnt;
}

__global__ __launch_bounds__(128, 1) void forward_kernel(
        const float* __restrict__ emit,
        const float* __restrict__ trans,
        const float* __restrict__ strans,
        const float* __restrict__ etrans,
        const int* __restrict__ lens,
        float* __restrict__ logZ_out) {
    const int b = blockIdx.x;
    const int j = threadIdx.x;  // column 0..127; wave0: j<64, wave1: j>=64

    __shared__ float bufA[N_ST];
    __shared__ float bufB[N_ST];
    __shared__ float red[2];

    // E[i] = exp(trans[i][j]) -- full column in registers, reused len times.
    float E[N_ST];
    #pragma unroll
    for (int i = 0; i < N_ST; ++i) E[i] = __expf(trans[i * N_ST + j]);

    const int len = lens[b];
    const float* eb = emit + (size_t)b * N_ST;
    const size_t TS = (size_t)B_SZ * N_ST;

    // a_0 = exp(strans + emit[0]) ; running shift Macc (alpha = Macc + log a)
    bufA[j] = __expf(strans[j] + eb[j]);
    float Macc = 0.0f;
    float* cur = bufA;
    float* nxt = bufB;
    float e_cur = eb[TS + j];  // emit[1] (len >= 256 so always valid)
    __syncthreads();

    for (int t = 1; t < len; ++t) {
        const int tn = (t + 1 < len) ? (t + 1) : (len - 1);
        const float e_next = eb[(size_t)tn * TS + j];  // prefetch, 1 iter of slack
        const float ee = __expf(e_cur);                // hidden under FMA chain

        // s_j = sum_i a_i * E[i][j] ; broadcast reads of cur[] (conflict-free)
        float s0 = 0.f, s1 = 0.f, s2 = 0.f, s3 = 0.f;
        const float4* a4 = (const float4*)cur;
        float rcp0 = 0.f;
        #pragma unroll
        for (int k = 0; k < 32; ++k) {
            float4 av = a4[k];
            if (k == 0) rcp0 = __builtin_amdgcn_rcpf(av.x);  // uniform normalizer 1/a[0]
            s0 = fmaf(av.x, E[4 * k + 0], s0);
            s1 = fmaf(av.y, E[4 * k + 1], s1);
            s2 = fmaf(av.z, E[4 * k + 2], s2);
            s3 = fmaf(av.w, E[4 * k + 3], s3);
        }
        const float s = (s0 + s1) + (s2 + s3);
        Macc -= __logf(rcp0);          // exact shift bookkeeping (off critical path)
        nxt[j] = ee * s * rcp0;        // a' = exp(emit) * s / a0
        float* tmp = cur; cur = nxt; nxt = tmp;
        e_cur = e_next;
        __syncthreads();               // single barrier: publish nxt, WAR-safe via ping-pong
    }

    // logZ_b = Macc + log( sum_j a_j * exp(etrans_j) )
    float v = cur[j] * __expf(etrans[j]);
    #pragma unroll
    for (int off = 1; off < 64; off <<= 1) v += __shfl_xor(v, off);
    if ((j & 63) == 0) red[j >> 6] = v;
    __syncthreads();
    if (j == 0) logZ_out[b] = Macc + __logf(red[0] + red[1]);
}

__global__ __launch_bounds__(128) void score_kernel(
        const float* __restrict__ emit,
        const int* __restrict__ target,
        const float* __restrict__ trans,
        const float* __restrict__ strans,
        const float* __restrict__ etrans,
        const int* __restrict__ lens,
        float* __restrict__ score_out) {
    const int b   = blockIdx.x;
    const int tid = threadIdx.x;  // 128
    const int len = lens[b];
    float local = 0.f;
    for (int t = tid; t < len; t += 128) {
        int tgt = target[t * B_SZ + b];
        float v = emit[(size_t)t * (B_SZ * N_ST) + b * N_ST + tgt];
        if (t > 0) v += trans[target[(t - 1) * B_SZ + b] * N_ST + tgt];
        local += v;
    }
    if (tid == 0) {
        local += strans[target[b]];
        local += etrans[target[(len - 1) * B_SZ + b]];
    }
    #pragma unroll
    for (int off = 1; off < 64; off <<= 1) local += __shfl_xor(local, off);
    __shared__ float partial[2];
    if ((tid & 63) == 0) partial[tid >> 6] = local;
    __syncthreads();
    if (tid == 0) score_out[b] = partial[0] + partial[1];
}

__global__ __launch_bounds__(256) void finalize_kernel(
        const float* __restrict__ logZ,
        const float* __restrict__ score,
        float* __restrict__ out) {
    int tid = threadIdx.x;  // 256
    float v = logZ[tid] - score[tid];
    #pragma unroll
    for (int off = 1; off < 64; off <<= 1) v += __shfl_xor(v, off);
    __shared__ float p[4];
    if ((tid & 63) == 0) p[tid >> 6] = v;
    __syncthreads();
    if (tid == 0) out[0] = (p[0] + p[1] + p[2] + p[3]) / 256.0f;
}

extern "C" void kernel_launch(void* const* d_in, const int* in_sizes, int n_in,
                              void* d_out, int out_size, void* d_ws, size_t ws_size,
                              hipStream_t stream) {
    const float*         emit   = (const float*)d_in[0];
    const int*           target = (const int*)d_in[1];
    const unsigned char* mask   = (const unsigned char*)d_in[2];
    const float*         trans  = (const float*)d_in[3];
    const float*         strans = (const float*)d_in[4];
    const float*         etrans = (const float*)d_in[5];

    float* ws     = (float*)d_ws;
    float* logZb  = ws;            // 256
    float* scoreb = ws + 256;      // 256
    int*   lens   = (int*)(ws + 512);

    lengths_kernel<<<B_SZ, 64, 0, stream>>>(mask, lens);
    forward_kernel<<<B_SZ, 128, 0, stream>>>(emit, trans, strans, etrans, lens, logZb);
    score_kernel<<<B_SZ, 128, 0, stream>>>(emit, target, trans, strans, etrans, lens, scoreb);
    finalize_kernel<<<1, 256, 0, stream>>>(logZb, scoreb, (float*)d_out);
}